// Round 14
// baseline (43.469 us; speedup 1.0000x reference)
//
#include <hip/hip_runtime.h>

#define BATCH 32
#define SS 1024
#define NSTEPS 972
#define LSTR 20                     // floats per lane row: 16 data + 4 pad = 80B (16B-aligned)

#define UNVIS   0x7F000000u         // huge finite float sentinels: UNVIS < CLOSED < OBST, all > any real f
#define CLOSEDB 0x7F000001u
#define OBSTB   0x7F000002u

typedef unsigned long long ull;

template <int CTRL>
__device__ __forceinline__ int dpp32(int v) {
    return __builtin_amdgcn_update_dpp(v, v, CTRL, 0xF, 0xF, false);
}

// 64-lane f32 min, result (bit-exact copy of some input) broadcast via readlane(63).
__device__ __forceinline__ float wave_min_f32_bcast(float v) {
    float t;
    t = __int_as_float(dpp32<0xB1 >(__float_as_int(v))); v = fminf(v, t);  // quad xor1
    t = __int_as_float(dpp32<0x4E >(__float_as_int(v))); v = fminf(v, t);  // quad xor2
    t = __int_as_float(dpp32<0x141>(__float_as_int(v))); v = fminf(v, t);  // row_half_mirror
    t = __int_as_float(dpp32<0x140>(__float_as_int(v))); v = fminf(v, t);  // row_mirror
    t = __int_as_float(dpp32<0x142>(__float_as_int(v))); v = fminf(v, t);  // row_bcast15
    t = __int_as_float(dpp32<0x143>(__float_as_int(v))); v = fminf(v, t);  // row_bcast31
    return __int_as_float(__builtin_amdgcn_readlane(__float_as_int(v), 63));
}

// min within each 8-lane group, butterfly (lane 0 of the group holds the min)
__device__ __forceinline__ float grp8_min_f32(float v) {
    float t;
    t = __int_as_float(dpp32<0xB1 >(__float_as_int(v))); v = fminf(v, t);
    t = __int_as_float(dpp32<0x4E >(__float_as_int(v))); v = fminf(v, t);
    t = __int_as_float(dpp32<0x141>(__float_as_int(v))); v = fminf(v, t);
    return v;
}

__device__ __forceinline__ unsigned umin2(unsigned a, unsigned b) { return a < b ? a : b; }
__device__ __forceinline__ unsigned slotc(float v, unsigned lm, unsigned i) {
    return (__float_as_uint(v) == lm) ? i : 63u;   // lane-local slot candidate
}

// patch: slot S of the owner lane -> exact finite CLOSEDB sentinel (NO bit-OR: OR of
// CLOSEDB into live f-bits can set exponent 0xFF -> NaN, which poisoned R13's min tree)
template <int S>
__device__ __forceinline__ float patchf(float K, unsigned csel) {
    return (csel == (unsigned)S) ? __uint_as_float(CLOSEDB) : K;   // v_cmp_eq + v_cndmask
}

__global__ __launch_bounds__(64)
void astar_kernel(const float* __restrict__ start_maps,
                  const float* __restrict__ goal_maps,
                  const float* __restrict__ obst_maps,
                  float* __restrict__ out)
{
    const int b = blockIdx.x;
    const int lane = threadIdx.x;

    __shared__ __align__(16) float fop[64 * LSTR];   // padded: cell c at (c>>4)*LSTR + (c&15)
    __shared__ __align__(16) float g_s[SS];
    __shared__ unsigned short par_s[SS];
    __shared__ int sh_start, sh_goal;

    const float* st = start_maps + b * SS;
    const float* gl = goal_maps + b * SS;
    const float* ob = obst_maps + b * SS;

    for (int i = 0; i < 16; ++i) {
        int c = i * 64 + lane;
        if (st[c] > 0.5f) sh_start = c;
        if (gl[c] > 0.5f) sh_goal = c;
    }
    __syncthreads();
    const int start_idx = sh_start;
    const int goal_idx = sh_goal;
    const float gi = (float)(goal_idx >> 5);
    const float gj = (float)(goal_idx & 31);
    const float SQRT2F = 1.41421356237309515f;   // fl32(sqrt(2))
    const float WH = 0.501f;
    const float INFF = __int_as_float(0x7f800000);
    const float CB = __uint_as_float(CLOSEDB);

    for (int i = 0; i < 16; ++i) {
        int c = i * 64 + lane;
        g_s[c] = 0.0f;
        par_s[c] = (unsigned short)goal_idx;
        fop[(c >> 4) * LSTR + (c & 15)] = __uint_as_float(ob[c] > 0.5f ? UNVIS : OBSTB);
    }
    __syncthreads();
    // NOTE: start's f is never written. sel_0 = start is hardcoded; the bank's all-sentinel
    // view IS the post-close_0 state (patch handles the close, fresh handles relax_0).

    const float* frow = &fop[lane * LSTR];
    float4 A0 = *(const float4*)(frow + 0);
    float4 A1 = *(const float4*)(frow + 4);
    float4 A2 = *(const float4*)(frow + 8);
    float4 A3 = *(const float4*)(frow + 12);
    float4 B0 = A0, B1 = A1, B2 = A2, B3 = A3;   // overwritten by first STEP's reload

    int sel = start_idx;
    bool solved = false;

    // One A* step. Tree bank t0..t3 = COMPLETE state after previous step
    // (closes <= t-1, relax <= t-1). Patch removes this step's close; fresh
    // keys cover this step's relax. Reload (post-writes) fills l0..l3 for next step.
    auto STEP = [&](float4& t0, float4& t1, float4& t2, float4& t3,
                    float4& l0, float4& l1, float4& l2, float4& l3)
    {
        solved = (sel == goal_idx);
        const int si = sel >> 5, sj = sel & 31;

        // ---- 1. close sel (neighbors never alias sel) ----
        if (lane == 0)
            fop[(sel >> 4) * LSTR + (sel & 15)] = CB;
        asm volatile("" ::: "memory");

        // ---- 2. relax input reads (gate the longest chain -> issue first) ----
        int k8 = lane < 8 ? (lane < 4 ? lane : lane + 1) : 4;
        int di = k8 / 3 - 1;
        int dj = k8 - (k8 / 3) * 3 - 1;
        int ni = si + di, nj = sj + dj;
        bool act = (lane < 8) && ((unsigned)ni < 32u) && ((unsigned)nj < 32u);
        int nb = act ? ni * 32 + nj : sel;
        int fa = (nb >> 4) * LSTR + (nb & 15);
        unsigned fbv = __float_as_uint(fop[fa]);   // dummy lanes read sel -> CLOSED -> rel=false
        float gnb = g_s[nb];
        float gsel = g_s[sel];

        // ---- 3. patch bank by sel (exact CLOSEDB), value tree, DPP, slot tree ----
        const unsigned csel = (lane == (sel >> 4)) ? (unsigned)(sel & 15) : 64u;
        float q00 = patchf<0 >(t0.x, csel), q01 = patchf<1 >(t0.y, csel);
        float q02 = patchf<2 >(t0.z, csel), q03 = patchf<3 >(t0.w, csel);
        float q04 = patchf<4 >(t1.x, csel), q05 = patchf<5 >(t1.y, csel);
        float q06 = patchf<6 >(t1.z, csel), q07 = patchf<7 >(t1.w, csel);
        float q08 = patchf<8 >(t2.x, csel), q09 = patchf<9 >(t2.y, csel);
        float q10 = patchf<10>(t2.z, csel), q11 = patchf<11>(t2.w, csel);
        float q12 = patchf<12>(t3.x, csel), q13 = patchf<13>(t3.y, csel);
        float q14 = patchf<14>(t3.z, csel), q15 = patchf<15>(t3.w, csel);
        float a0 = fminf(fminf(q00, q01), fminf(q02, q03));
        float a1 = fminf(fminf(q04, q05), fminf(q06, q07));
        float a2 = fminf(fminf(q08, q09), fminf(q10, q11));
        float a3 = fminf(fminf(q12, q13), fminf(q14, q15));
        float lmin = fminf(fminf(a0, a1), fminf(a2, a3));
        const unsigned lm = __float_as_uint(lmin);
        const float gs = wave_min_f32_bcast(lmin);      // stale global min (uniform)

        unsigned s0 = umin2(umin2(slotc(q00, lm, 0),  slotc(q01, lm, 1)),
                            umin2(slotc(q02, lm, 2),  slotc(q03, lm, 3)));
        unsigned s1 = umin2(umin2(slotc(q04, lm, 4),  slotc(q05, lm, 5)),
                            umin2(slotc(q06, lm, 6),  slotc(q07, lm, 7)));
        unsigned s2 = umin2(umin2(slotc(q08, lm, 8),  slotc(q09, lm, 9)),
                            umin2(slotc(q10, lm, 10), slotc(q11, lm, 11)));
        unsigned s3 = umin2(umin2(slotc(q12, lm, 12), slotc(q13, lm, 13)),
                            umin2(slotc(q14, lm, 14), slotc(q15, lm, 15)));
        unsigned slot = umin2(umin2(s0, s1), umin2(s2, s3));

        // ---- 4. fh arithmetic (reference-identical op order) + relax compute/writes ----
        float dxn = fabsf((float)ni - gi);
        float dyn = fabsf((float)nj - gj);
        float hn  = __fadd_rn(__fmul_rn(fminf(dxn, dyn), SQRT2F), fabsf(dxn - dyn));
        float fhn = __fmul_rn(WH, hn);
        float w = ((di != 0) && (dj != 0)) ? SQRT2F : 1.0f;
        float g2 = __fadd_rn(gsel, w);               // exact: fl(g_sel + w)
        bool rel = act && ((fbv == UNVIS) || (fbv < UNVIS && gnb > g2));
        float fnew = __fadd_rn(__fmul_rn(0.5f, g2), fhn);
        if (rel) {
            fop[fa] = fnew;
            g_s[nb] = g2;
            par_s[nb] = (unsigned short)sel;
        }
        asm volatile("" ::: "memory");

        // ---- 5. late reload: sees close_t + relax_t -> COMPLETE state for next step.
        //         Latency hidden: consumed next step after patch/resolve/merge. ----
        l0 = *(const float4*)(frow + 0);
        l1 = *(const float4*)(frow + 4);
        l2 = *(const float4*)(frow + 8);
        l3 = *(const float4*)(frow + 12);
        asm volatile("" ::: "memory");

        // ---- 6. fresh reduce over this step's relaxes (lanes 0-7, nb-ascending) ----
        float fv = rel ? fnew : INFF;                // fresh candidate (<= its bank copy)
        float fm = grp8_min_f32(fv);
        const float fmv = __int_as_float(__builtin_amdgcn_readlane(__float_as_int(fm), 0));

        // ---- 7. merge + resolve (R11 semantics, bit-exact tie-break by flat index) ----
        const float gmin = fminf(gs, fmv);
        const unsigned gb = __float_as_uint(gmin);
        const ull bal_s = __ballot(lm == gb);                       // bank matches
        const ull bal_f = __ballot(__float_as_uint(fv) == gb);      // fresh matches

        unsigned idx_s = 0xFFFFu, idx_f = 0xFFFFu;
        if (bal_s) {            // uniform branch (SGPR)
            int owner = (int)__builtin_ctzll(bal_s);                // lowest lane = lowest cell block
            idx_s = (unsigned)(owner * 16 + __builtin_amdgcn_readlane((int)slot, owner));
        }
        if (bal_f) {            // fresh lanes nb-ascending -> ctz = lowest fresh cell
            int fl = (int)__builtin_ctzll(bal_f);
            idx_f = (unsigned)__builtin_amdgcn_readlane(nb, fl);
        }
        sel = (int)umin2(idx_s, idx_f);   // equal values -> lowest flat index (exact tie-break)
    };

    #pragma unroll 1
    for (int t = 0; t < NSTEPS; t += 2) {
        STEP(A0, A1, A2, A3, B0, B1, B2, B3);   // tree on A, reload -> B
        if (solved) break;
        STEP(B0, B1, B2, B3, A0, A1, A2, A3);   // tree on B, reload -> A
        if (solved) break;
    }

    float* out_hist = out + b * SS;
    float* out_path = out + BATCH * SS + b * SS;
    float* out_g    = out + 2 * BATCH * SS + b * SS;
    for (int i = 0; i < 16; ++i) {
        int c = i * 64 + lane;
        unsigned fbv = __float_as_uint(fop[(c >> 4) * LSTR + (c & 15)]);
        out_hist[c] = (fbv == CLOSEDB) ? 1.0f : 0.0f;
        out_g[c]    = g_s[c];
        out_path[c] = (c == goal_idx) ? 1.0f : 0.0f;
    }
    __syncthreads();   // drain stores before backtrack overwrites
    if (lane == 0) {
        int loc = par_s[goal_idx];
        for (int it = 0; it < NSTEPS; ++it) {
            out_path[loc] = 1.0f;
            if (loc == goal_idx) break;   // parent chain strictly decreasing in expansion time
            loc = par_s[loc];
        }
    }
}

extern "C" void kernel_launch(void* const* d_in, const int* in_sizes, int n_in,
                              void* d_out, int out_size, void* d_ws, size_t ws_size,
                              hipStream_t stream)
{
    // d_in: [0]=cost_maps (unused in 'default' mode), [1]=start, [2]=goal, [3]=obstacles
    const float* start_maps = (const float*)d_in[1];
    const float* goal_maps  = (const float*)d_in[2];
    const float* obst_maps  = (const float*)d_in[3];
    float* out = (float*)d_out;
    hipLaunchKernelGGL(astar_kernel, dim3(BATCH), dim3(64), 0, stream,
                       start_maps, goal_maps, obst_maps, out);
}

// Round 15
// 40.649 us; speedup vs baseline: 1.0694x; 1.0694x over previous
//
#include <hip/hip_runtime.h>

#define BATCH 32
#define SS 1024
#define NSTEPS 972
#define LSTR 20                     // floats per lane row: 16 data + 4 pad = 80B (16B-aligned, 8-way bank spread)

#define UNVIS   0x7F000000u         // huge finite float sentinels: UNVIS < CLOSED < OBST, all > any real f
#define CLOSEDB 0x7F000001u
#define OBSTB   0x7F000002u

typedef unsigned long long ull;

template <int CTRL>
__device__ __forceinline__ int dpp32(int v) {
    return __builtin_amdgcn_update_dpp(v, v, CTRL, 0xF, 0xF, false);
}

// 64-lane f32 min, result (bit-exact copy of some input) broadcast via readlane(63).
__device__ __forceinline__ float wave_min_f32_bcast(float v) {
    float t;
    t = __int_as_float(dpp32<0xB1 >(__float_as_int(v))); v = fminf(v, t);  // quad xor1
    t = __int_as_float(dpp32<0x4E >(__float_as_int(v))); v = fminf(v, t);  // quad xor2
    t = __int_as_float(dpp32<0x141>(__float_as_int(v))); v = fminf(v, t);  // row_half_mirror
    t = __int_as_float(dpp32<0x140>(__float_as_int(v))); v = fminf(v, t);  // row_mirror
    t = __int_as_float(dpp32<0x142>(__float_as_int(v))); v = fminf(v, t);  // row_bcast15
    t = __int_as_float(dpp32<0x143>(__float_as_int(v))); v = fminf(v, t);  // row_bcast31
    return __int_as_float(__builtin_amdgcn_readlane(__float_as_int(v), 63));
}

// min within each 8-lane group, butterfly (lane 0 of the group holds the min)
__device__ __forceinline__ float grp8_min_f32(float v) {
    float t;
    t = __int_as_float(dpp32<0xB1 >(__float_as_int(v))); v = fminf(v, t);
    t = __int_as_float(dpp32<0x4E >(__float_as_int(v))); v = fminf(v, t);
    t = __int_as_float(dpp32<0x141>(__float_as_int(v))); v = fminf(v, t);
    return v;
}

__device__ __forceinline__ unsigned umin2(unsigned a, unsigned b) { return a < b ? a : b; }
__device__ __forceinline__ float fmin3(float a, float b, float c) { return fminf(fminf(a, b), c); }
__device__ __forceinline__ unsigned umin3(unsigned a, unsigned b, unsigned c) { return umin2(umin2(a, b), c); }
__device__ __forceinline__ unsigned slotc(float v, unsigned lm, unsigned i) {
    return (__float_as_uint(v) == lm) ? i : 63u;   // lane-local slot candidate
}

__global__ __launch_bounds__(64)
void astar_kernel(const float* __restrict__ start_maps,
                  const float* __restrict__ goal_maps,
                  const float* __restrict__ obst_maps,
                  float* __restrict__ out)
{
    const int b = blockIdx.x;
    const int lane = threadIdx.x;

    __shared__ __align__(16) float fop[64 * LSTR];   // padded: cell c at (c>>4)*LSTR + (c&15)
    __shared__ __align__(16) float g_s[SS];
    __shared__ __align__(16) float fh_s[SS];         // 0.501f * h (precomputed, ref op order)
    __shared__ unsigned short par_s[SS];
    __shared__ int sh_start, sh_goal;

    const float* st = start_maps + b * SS;
    const float* gl = goal_maps + b * SS;
    const float* ob = obst_maps + b * SS;

    for (int i = 0; i < 16; ++i) {
        int c = i * 64 + lane;
        if (st[c] > 0.5f) sh_start = c;
        if (gl[c] > 0.5f) sh_goal = c;
    }
    __syncthreads();
    const int start_idx = sh_start;
    const int goal_idx = sh_goal;
    const float gi = (float)(goal_idx >> 5);
    const float gj = (float)(goal_idx & 31);
    const float SQRT2F = 1.41421356237309515f;   // fl32(sqrt(2))
    const float WH = 0.501f;
    const float INFF = __int_as_float(0x7f800000);
    const float CB = __uint_as_float(CLOSEDB);

    for (int i = 0; i < 16; ++i) {
        int c = i * 64 + lane;
        float dx = fabsf((float)(c >> 5) - gi);
        float dy = fabsf((float)(c & 31) - gj);
        float h = __fadd_rn(__fmul_rn(fminf(dx, dy), SQRT2F), fabsf(dx - dy));
        fh_s[c] = __fmul_rn(WH, h);
        g_s[c] = 0.0f;
        par_s[c] = (unsigned short)goal_idx;
        fop[(c >> 4) * LSTR + (c & 15)] = __uint_as_float(ob[c] > 0.5f ? UNVIS : OBSTB);
    }
    __syncthreads();
    if (lane == 0)
        fop[(start_idx >> 4) * LSTR + (start_idx & 15)] = fh_s[start_idx];  // f = fl(0.5*0 + fh) = fh
    __syncthreads();

    const float* frow = &fop[lane * LSTR];
    int sel = start_idx;             // first selection is trivially the start cell

    // lane-constant relax geometry (hoisted: only ni/nj/act/nb depend on sel)
    const int k8 = lane < 8 ? (lane < 4 ? lane : lane + 1) : 4;
    const int di = k8 / 3 - 1;
    const int dj = k8 - (k8 / 3) * 3 - 1;
    const float w = ((di != 0) && (dj != 0)) ? SQRT2F : 1.0f;
    const bool lane8 = (lane < 8);

    #pragma unroll 1
    for (int step = 0; step < NSTEPS; ++step) {
        const bool solved = (sel == goal_idx);
        const int si = sel >> 5, sj = sel & 31;

        // ---- 1. close sel (neighbors never alias sel) ----
        if (lane == 0)
            fop[(sel >> 4) * LSTR + (sel & 15)] = CB;
        asm volatile("" ::: "memory");

        // ---- 2. relax input reads first (they gate the longest dependent chain) ----
        int ni = si + di, nj = sj + dj;
        bool act = lane8 && ((unsigned)ni < 32u) && ((unsigned)nj < 32u);
        int nb = act ? ni * 32 + nj : sel;
        int fa = (nb >> 4) * LSTR + (nb & 15);
        unsigned fbv = __float_as_uint(fop[fa]);   // dummy lanes read sel -> CLOSED -> rel=false
        float gnb = g_s[nb];
        float fhn = fh_s[nb];
        float gsel = g_s[sel];

        // ---- 3. scan loads: AFTER close (sees it), BEFORE relax writes (stale wrt them) ----
        float4 r0 = *(const float4*)(frow + 0);
        float4 r1 = *(const float4*)(frow + 4);
        float4 r2 = *(const float4*)(frow + 8);
        float4 r3 = *(const float4*)(frow + 12);
        asm volatile("" ::: "memory");

        // ---- 4. relax compute + writes ----
        float g2 = __fadd_rn(gsel, w);               // exact: fl(g_sel + w)
        bool rel = act && ((fbv == UNVIS) || (fbv < UNVIS && gnb > g2));
        float fnew = __fadd_rn(__fmul_rn(0.5f, g2), fhn);
        if (rel) {
            fop[fa] = fnew;                          // next iter's scan sees this; this iter's doesn't
            g_s[nb] = g2;
            par_s[nb] = (unsigned short)sel;
        }
        if (solved) break;   // relax of the solved step applied (matches reference)

        // ---- 5. value tree (min3 shape) over stale scan + fresh fv merged in-resolve ----
        float fv = rel ? fnew : INFF;                // fresh candidate (strictly < its stale copy)
        float a0 = fminf(fmin3(r0.x, r0.y, r0.z), r0.w);
        float a1 = fminf(fmin3(r1.x, r1.y, r1.z), r1.w);
        float a2 = fminf(fmin3(r2.x, r2.y, r2.z), r2.w);
        float a3 = fminf(fmin3(r3.x, r3.y, r3.z), r3.w);
        float lmin = fminf(fmin3(a0, a1, a2), a3);
        const unsigned lm = __float_as_uint(lmin);
        const float gs = wave_min_f32_bcast(fminf(lmin, fv));   // global min incl fresh
        const unsigned gb = __float_as_uint(gs);

        // slot tree (umin3 shape): independent of DPP chain -> fills its hazard gaps
        unsigned s0 = umin3(umin3(slotc(r0.x, lm, 0),  slotc(r0.y, lm, 1),  slotc(r0.z, lm, 2)),
                            umin3(slotc(r0.w, lm, 3),  slotc(r1.x, lm, 4),  slotc(r1.y, lm, 5)),
                            umin2(slotc(r1.z, lm, 6),  slotc(r1.w, lm, 7)));
        unsigned s1 = umin3(umin3(slotc(r2.x, lm, 8),  slotc(r2.y, lm, 9),  slotc(r2.z, lm, 10)),
                            umin3(slotc(r2.w, lm, 11), slotc(r3.x, lm, 12), slotc(r3.y, lm, 13)),
                            umin2(slotc(r3.z, lm, 14), slotc(r3.w, lm, 15)));
        unsigned slot = umin2(s0, s1);

        // ---- 6. branchless resolve (no uniform branches; garbage lanes masked after) ----
        const ull bal_s = __ballot(lm == gb);                       // stale matches
        const ull bal_f = __ballot(__float_as_uint(fv) == gb);      // fresh matches (INF never)
        const int owner_s = (int)__builtin_ctzll(bal_s | (1ull << 63));
        const int owner_f = (int)__builtin_ctzll(bal_f | (1ull << 63));
        unsigned raw_s = (unsigned)(owner_s * 16 + __builtin_amdgcn_readlane((int)slot, owner_s));
        unsigned raw_f = (unsigned)__builtin_amdgcn_readlane(nb, owner_f);
        unsigned idx_s = bal_s ? raw_s : 0xFFFFu;   // scalar cselect, no branch
        unsigned idx_f = bal_f ? raw_f : 0xFFFFu;
        sel = (int)umin2(idx_s, idx_f);   // equal values -> lowest flat index (exact tie-break)
    }

    float* out_hist = out + b * SS;
    float* out_path = out + BATCH * SS + b * SS;
    float* out_g    = out + 2 * BATCH * SS + b * SS;
    for (int i = 0; i < 16; ++i) {
        int c = i * 64 + lane;
        unsigned fbv = __float_as_uint(fop[(c >> 4) * LSTR + (c & 15)]);
        out_hist[c] = (fbv == CLOSEDB) ? 1.0f : 0.0f;
        out_g[c]    = g_s[c];
        out_path[c] = (c == goal_idx) ? 1.0f : 0.0f;
    }
    __syncthreads();   // drain stores before backtrack overwrites
    if (lane == 0) {
        int loc = par_s[goal_idx];
        for (int it = 0; it < NSTEPS; ++it) {
            out_path[loc] = 1.0f;
            if (loc == goal_idx) break;   // parent chain strictly decreasing in expansion time
            loc = par_s[loc];
        }
    }
}

extern "C" void kernel_launch(void* const* d_in, const int* in_sizes, int n_in,
                              void* d_out, int out_size, void* d_ws, size_t ws_size,
                              hipStream_t stream)
{
    // d_in: [0]=cost_maps (unused in 'default' mode), [1]=start, [2]=goal, [3]=obstacles
    const float* start_maps = (const float*)d_in[1];
    const float* goal_maps  = (const float*)d_in[2];
    const float* obst_maps  = (const float*)d_in[3];
    float* out = (float*)d_out;
    hipLaunchKernelGGL(astar_kernel, dim3(BATCH), dim3(64), 0, stream,
                       start_maps, goal_maps, obst_maps, out);
}